// Round 4
// baseline (782.637 us; speedup 1.0000x reference)
//
#include <hip/hip_runtime.h>

#define S_DIM 64
#define B_DIM 128
#define D_DIM 10000
#define NV4   2500          // D_DIM / 4
#define BLOCK 512
#define KMAX  5             // ceil(NV4/BLOCK); k<4 always valid, k==4 iff tid<452
#define NROWS (S_DIM * B_DIM)
#define NWAVE (BLOCK / 64)

typedef float floatx4 __attribute__((ext_vector_type(4)));  // clang-native vec4

// One workgroup per (s,b) row; exp values in registers (20 VGPRs of data).
// Noise read from HBM exactly once with nontemporal loads (keeps reused
// theta/y L2-resident). Max-subtraction skipped: eta ~ N(0, sqrt(2)), max ~8.5
// over the dataset, exp() safe in fp32; softmax is shift-invariant.
// Last-finishing block performs the deterministic fixed-order final reduce.
__global__ __launch_bounds__(BLOCK, 8) void perturbed_loss_fused(
    const float* __restrict__ theta,   // [B, D]
    const float* __restrict__ y,       // [B, D]
    const float* __restrict__ noise,   // [S, B, D]
    float* __restrict__ partials,      // [NROWS] per-row SSE
    unsigned int* __restrict__ counter,// zeroed by hipMemsetAsync each call
    float* __restrict__ out)
{
    __shared__ float red[NWAVE];
    __shared__ double dred[NWAVE];
    __shared__ int is_last;

    const int blk  = blockIdx.x;           // row id in [0, NROWS)
    const int b    = blk % B_DIM;
    const int tid  = threadIdx.x;
    const int lane = tid & 63;
    const int wave = tid >> 6;

    const float4*  th4 = reinterpret_cast<const float4*>(theta + (size_t)b * D_DIM);
    const float4*  y4  = reinterpret_cast<const float4*>(y     + (size_t)b * D_DIM);
    const floatx4* nz4 = reinterpret_cast<const floatx4*>(noise + (size_t)blk * D_DIM);

    // ---- Pass 1: ex = exp(theta + noise) -> registers, fused sum ----
    float4 ex[KMAX];
    float sm = 0.0f;
    #pragma unroll
    for (int k = 0; k < KMAX; ++k) {
        const int i = tid + k * BLOCK;
        if (k < KMAX - 1 || i < NV4) {
            float4  t = th4[i];
            floatx4 n = __builtin_nontemporal_load(&nz4[i]);
            float4 e;
            e.x = __expf(t.x + n.x);
            e.y = __expf(t.y + n.y);
            e.z = __expf(t.z + n.z);
            e.w = __expf(t.w + n.w);
            ex[k] = e;
            sm += (e.x + e.y) + (e.z + e.w);
        }
    }
    #pragma unroll
    for (int o = 32; o > 0; o >>= 1) sm += __shfl_down(sm, o, 64);
    if (lane == 0) red[wave] = sm;
    __syncthreads();
    float tot = 0.0f;
    #pragma unroll
    for (int w = 0; w < NWAVE; ++w) tot += red[w];
    const float inv = 1.0f / tot;

    // ---- Pass 2: sum (ex*inv - y)^2 ----
    float acc = 0.0f;
    #pragma unroll
    for (int k = 0; k < KMAX; ++k) {
        const int i = tid + k * BLOCK;
        if (k < KMAX - 1 || i < NV4) {
            float4 e  = ex[k];
            float4 yy = y4[i];
            float dx = fmaf(e.x, inv, -yy.x); acc = fmaf(dx, dx, acc);
            float dy = fmaf(e.y, inv, -yy.y); acc = fmaf(dy, dy, acc);
            float dz = fmaf(e.z, inv, -yy.z); acc = fmaf(dz, dz, acc);
            float dw = fmaf(e.w, inv, -yy.w); acc = fmaf(dw, dw, acc);
        }
    }
    #pragma unroll
    for (int o = 32; o > 0; o >>= 1) acc += __shfl_down(acc, o, 64);
    __syncthreads();                    // red[] reads above done before rewrite
    if (lane == 0) red[wave] = acc;
    __syncthreads();

    // ---- Completion: last block reduces all partials (fixed order) ----
    if (tid == 0) {
        float total = 0.0f;
        #pragma unroll
        for (int w = 0; w < NWAVE; ++w) total += red[w];
        __hip_atomic_store(&partials[blk], total, __ATOMIC_RELEASE,
                           __HIP_MEMORY_SCOPE_AGENT);
        unsigned int old = __hip_atomic_fetch_add(counter, 1u, __ATOMIC_ACQ_REL,
                                                  __HIP_MEMORY_SCOPE_AGENT);
        is_last = (old == (unsigned int)(gridDim.x - 1)) ? 1 : 0;
    }
    __syncthreads();
    if (is_last) {
        double s = 0.0;
        for (int i = tid; i < NROWS; i += BLOCK)
            s += (double)__hip_atomic_load(&partials[i], __ATOMIC_RELAXED,
                                           __HIP_MEMORY_SCOPE_AGENT);
        #pragma unroll
        for (int o = 32; o > 0; o >>= 1) s += __shfl_down(s, o, 64);
        if (lane == 0) dred[wave] = s;
        __syncthreads();
        if (tid == 0) {
            double t = 0.0;
            #pragma unroll
            for (int w = 0; w < NWAVE; ++w) t += dred[w];
            out[0] = (float)(t / ((double)S_DIM * (double)B_DIM * (double)D_DIM));
        }
    }
}

extern "C" void kernel_launch(void* const* d_in, const int* in_sizes, int n_in,
                              void* d_out, int out_size, void* d_ws, size_t ws_size,
                              hipStream_t stream) {
    const float* theta = (const float*)d_in[0];
    const float* y     = (const float*)d_in[1];
    const float* noise = (const float*)d_in[2];
    float* out      = (float*)d_out;
    float* partials = (float*)d_ws;                        // NROWS floats
    unsigned int* counter = (unsigned int*)((char*)d_ws + NROWS * sizeof(float));

    (void)hipMemsetAsync(counter, 0, sizeof(unsigned int), stream);
    perturbed_loss_fused<<<NROWS, BLOCK, 0, stream>>>(theta, y, noise,
                                                      partials, counter, out);
}

// Round 5
// 717.841 us; speedup vs baseline: 1.0903x; 1.0903x over previous
//
#include <hip/hip_runtime.h>

#define S_DIM 64
#define B_DIM 128
#define D_DIM 10000
#define NV4   2500          // D_DIM / 4
#define BLOCK 256
#define KMAX  10            // ceil(NV4/BLOCK); k<9 always valid, k==9 iff tid<196
#define NROWS (S_DIM * B_DIM)
#define NWAVE (BLOCK / 64)

// One workgroup per (s,b) row; exp values held in registers (40 VGPRs of
// data). No LDS staging: noise read from HBM exactly once, single fused pass.
// NO __launch_bounds__ min-wave clamp: round 4 proved that squeezing to 64
// VGPR spills ex[] to scratch (VGPR_Count=28, 783us). Let allocator take ~100.
// Max-subtraction skipped: eta ~ N(0, sqrt(2)), dataset max ~8.5, exp() safe
// in fp32; softmax is shift-invariant so the result is unchanged.
// Last-finishing block does the deterministic fixed-order final reduction.
__global__ __launch_bounds__(BLOCK) void perturbed_loss_fused(
    const float* __restrict__ theta,   // [B, D]
    const float* __restrict__ y,       // [B, D]
    const float* __restrict__ noise,   // [S, B, D]
    float* __restrict__ partials,      // [NROWS] per-row SSE
    unsigned int* __restrict__ counter,// zeroed by hipMemsetAsync each call
    float* __restrict__ out)
{
    __shared__ float red[NWAVE];
    __shared__ double dred[NWAVE];
    __shared__ int is_last;

    const int blk  = blockIdx.x;           // row id in [0, NROWS)
    const int b    = blk % B_DIM;
    const int tid  = threadIdx.x;
    const int lane = tid & 63;
    const int wave = tid >> 6;

    const float4* th4 = reinterpret_cast<const float4*>(theta + (size_t)b * D_DIM);
    const float4* y4  = reinterpret_cast<const float4*>(y     + (size_t)b * D_DIM);
    const float4* nz4 = reinterpret_cast<const float4*>(noise + (size_t)blk * D_DIM);

    // ---- Pass 1: ex = exp(theta + noise) -> registers, fused sum ----
    float4 ex[KMAX];
    float sm = 0.0f;
    #pragma unroll
    for (int k = 0; k < KMAX; ++k) {
        const int i = tid + k * BLOCK;
        if (k < KMAX - 1 || i < NV4) {
            float4 t = th4[i];
            float4 n = nz4[i];
            float4 e;
            e.x = __expf(t.x + n.x);
            e.y = __expf(t.y + n.y);
            e.z = __expf(t.z + n.z);
            e.w = __expf(t.w + n.w);
            ex[k] = e;
            sm += (e.x + e.y) + (e.z + e.w);
        }
    }
    #pragma unroll
    for (int o = 32; o > 0; o >>= 1) sm += __shfl_down(sm, o, 64);
    if (lane == 0) red[wave] = sm;
    __syncthreads();
    float tot = 0.0f;
    #pragma unroll
    for (int w = 0; w < NWAVE; ++w) tot += red[w];
    const float inv = 1.0f / tot;

    // ---- Pass 2: sum (ex*inv - y)^2 ----
    float acc = 0.0f;
    #pragma unroll
    for (int k = 0; k < KMAX; ++k) {
        const int i = tid + k * BLOCK;
        if (k < KMAX - 1 || i < NV4) {
            float4 e  = ex[k];
            float4 yy = y4[i];
            float dx = fmaf(e.x, inv, -yy.x); acc = fmaf(dx, dx, acc);
            float dy = fmaf(e.y, inv, -yy.y); acc = fmaf(dy, dy, acc);
            float dz = fmaf(e.z, inv, -yy.z); acc = fmaf(dz, dz, acc);
            float dw = fmaf(e.w, inv, -yy.w); acc = fmaf(dw, dw, acc);
        }
    }
    #pragma unroll
    for (int o = 32; o > 0; o >>= 1) acc += __shfl_down(acc, o, 64);
    __syncthreads();                    // red[] reads above done before rewrite
    if (lane == 0) red[wave] = acc;
    __syncthreads();

    // ---- Completion: last block reduces all partials (fixed order) ----
    if (tid == 0) {
        float total = 0.0f;
        #pragma unroll
        for (int w = 0; w < NWAVE; ++w) total += red[w];
        __hip_atomic_store(&partials[blk], total, __ATOMIC_RELEASE,
                           __HIP_MEMORY_SCOPE_AGENT);
        unsigned int old = __hip_atomic_fetch_add(counter, 1u, __ATOMIC_ACQ_REL,
                                                  __HIP_MEMORY_SCOPE_AGENT);
        is_last = (old == (unsigned int)(gridDim.x - 1)) ? 1 : 0;
    }
    __syncthreads();
    if (is_last) {
        double s = 0.0;
        for (int i = tid; i < NROWS; i += BLOCK)
            s += (double)__hip_atomic_load(&partials[i], __ATOMIC_RELAXED,
                                           __HIP_MEMORY_SCOPE_AGENT);
        #pragma unroll
        for (int o = 32; o > 0; o >>= 1) s += __shfl_down(s, o, 64);
        if (lane == 0) dred[wave] = s;
        __syncthreads();
        if (tid == 0) {
            double t = 0.0;
            #pragma unroll
            for (int w = 0; w < NWAVE; ++w) t += dred[w];
            out[0] = (float)(t / ((double)S_DIM * (double)B_DIM * (double)D_DIM));
        }
    }
}

extern "C" void kernel_launch(void* const* d_in, const int* in_sizes, int n_in,
                              void* d_out, int out_size, void* d_ws, size_t ws_size,
                              hipStream_t stream) {
    const float* theta = (const float*)d_in[0];
    const float* y     = (const float*)d_in[1];
    const float* noise = (const float*)d_in[2];
    float* out      = (float*)d_out;
    float* partials = (float*)d_ws;                        // NROWS floats
    unsigned int* counter = (unsigned int*)((char*)d_ws + NROWS * sizeof(float));

    (void)hipMemsetAsync(counter, 0, sizeof(unsigned int), stream);
    perturbed_loss_fused<<<NROWS, BLOCK, 0, stream>>>(theta, y, noise,
                                                      partials, counter, out);
}

// Round 6
// 89.317 us; speedup vs baseline: 8.7625x; 8.0370x over previous
//
#include <hip/hip_runtime.h>

#define S_DIM 64
#define B_DIM 128
#define D_DIM 10000
#define NV4   2500          // D_DIM / 4
#define BLOCK 256
#define KMAX  10            // ceil(NV4/BLOCK); k<9 always valid, k==9 iff tid<196
#define NROWS (S_DIM * B_DIM)

// One workgroup per (s,b) row; exp values held in registers (40 VGPRs of
// data). No LDS staging: noise read from HBM exactly once, single fused pass.
// EXACT round-2 structure (87.5us, no spill): two kernels, plain
// __launch_bounds__(256). Rounds 4/5 proved that adding a fused reduction
// tail makes the allocator collapse to 28-40 VGPR and spill ex[] (718-783us).
//
// Row mapping: b = blk>>6, s = blk&63 — consecutive blocks share the same
// theta/y row, so each XCD's resident blocks touch only ~16 distinct b
// values (~1.3 MB) -> theta/y become L2-resident instead of thrashing
// through L3/fabric (10.2 MB working set > 4 MB per-XCD L2 with the old
// s-major mapping).
//
// Max-subtraction skipped: eta ~ N(0, sqrt(2)), dataset max ~8.5, exp() safe
// in fp32; softmax is shift-invariant so the result is unchanged.
__global__ __launch_bounds__(BLOCK) void perturbed_loss_row(
    const float* __restrict__ theta,   // [B, D]
    const float* __restrict__ y,       // [B, D]
    const float* __restrict__ noise,   // [S, B, D]
    float* __restrict__ partials)      // [NROWS] raw per-row SSE
{
    __shared__ float red[4];

    const int blk = blockIdx.x;            // in [0, NROWS)
    const int b   = blk >> 6;              // [0, 128) — shared by 64 consecutive blocks
    const int s   = blk & 63;              // [0, 64)
    const int tid  = threadIdx.x;
    const int lane = tid & 63;
    const int wave = tid >> 6;

    const float4* th4 = reinterpret_cast<const float4*>(theta + (size_t)b * D_DIM);
    const float4* y4  = reinterpret_cast<const float4*>(y     + (size_t)b * D_DIM);
    const float4* nz4 = reinterpret_cast<const float4*>(
        noise + ((size_t)s * B_DIM + b) * D_DIM);

    // ---- Pass 1: ex = exp(theta + noise) -> registers, fused sum ----
    float4 ex[KMAX];
    float sm = 0.0f;
    #pragma unroll
    for (int k = 0; k < KMAX; ++k) {
        const int i = tid + k * BLOCK;
        if (k < KMAX - 1 || i < NV4) {
            float4 t = th4[i];
            float4 n = nz4[i];
            float4 e;
            e.x = __expf(t.x + n.x);
            e.y = __expf(t.y + n.y);
            e.z = __expf(t.z + n.z);
            e.w = __expf(t.w + n.w);
            ex[k] = e;
            sm += (e.x + e.y) + (e.z + e.w);
        }
    }
    #pragma unroll
    for (int o = 32; o > 0; o >>= 1) sm += __shfl_down(sm, o, 64);
    if (lane == 0) red[wave] = sm;
    __syncthreads();
    const float inv = 1.0f / ((red[0] + red[1]) + (red[2] + red[3]));

    // ---- Pass 2: sum (ex*inv - y)^2 ----
    float acc = 0.0f;
    #pragma unroll
    for (int k = 0; k < KMAX; ++k) {
        const int i = tid + k * BLOCK;
        if (k < KMAX - 1 || i < NV4) {
            float4 e  = ex[k];
            float4 yy = y4[i];
            float dx = fmaf(e.x, inv, -yy.x); acc = fmaf(dx, dx, acc);
            float dy = fmaf(e.y, inv, -yy.y); acc = fmaf(dy, dy, acc);
            float dz = fmaf(e.z, inv, -yy.z); acc = fmaf(dz, dz, acc);
            float dw = fmaf(e.w, inv, -yy.w); acc = fmaf(dw, dw, acc);
        }
    }
    #pragma unroll
    for (int o = 32; o > 0; o >>= 1) acc += __shfl_down(acc, o, 64);
    __syncthreads();                    // red[] reads above done before rewrite
    if (lane == 0) red[wave] = acc;
    __syncthreads();
    if (tid == 0) partials[blk] = ((red[0] + red[1]) + (red[2] + red[3]));
}

// Deterministic fixed-order reduction of the 8192 per-row partials.
__global__ __launch_bounds__(BLOCK) void reduce_partials(
    const float* __restrict__ partials,
    float* __restrict__ out)
{
    __shared__ double red[4];
    const int tid  = threadIdx.x;
    const int lane = tid & 63;
    const int wave = tid >> 6;

    double s = 0.0;
    for (int i = tid; i < NROWS; i += BLOCK) s += (double)partials[i];
    #pragma unroll
    for (int o = 32; o > 0; o >>= 1) s += __shfl_down(s, o, 64);
    if (lane == 0) red[wave] = s;
    __syncthreads();
    if (tid == 0) {
        double t = ((red[0] + red[1]) + (red[2] + red[3]));
        out[0] = (float)(t / ((double)S_DIM * (double)B_DIM * (double)D_DIM));
    }
}

extern "C" void kernel_launch(void* const* d_in, const int* in_sizes, int n_in,
                              void* d_out, int out_size, void* d_ws, size_t ws_size,
                              hipStream_t stream) {
    const float* theta = (const float*)d_in[0];
    const float* y     = (const float*)d_in[1];
    const float* noise = (const float*)d_in[2];
    float* out      = (float*)d_out;
    float* partials = (float*)d_ws;   // NROWS floats = 32 KB scratch

    perturbed_loss_row<<<NROWS, BLOCK, 0, stream>>>(theta, y, noise, partials);
    reduce_partials<<<1, BLOCK, 0, stream>>>(partials, out);
}